// Round 2
// baseline (1650.249 us; speedup 1.0000x reference)
//
#include <hip/hip_runtime.h>
#include <math.h>

// ---------------------------------------------------------------------------
// CSDM pipeline on MI355X. fp32 in/out (per reference dtypes), fp32
// intermediates in d_ws (~145 MB). B=4, C=32, H=W=256.
// ---------------------------------------------------------------------------

constexpr int B = 4, C = 32, H = 256, W = 256;
constexpr int HW = H * W;                      // 65536
constexpr int H1 = 128, W1 = 128, HW1 = H1 * W1;
constexpr int H2 = 64,  W2 = 64,  HW2 = H2 * W2;
constexpr int CH = 16;   // head hidden channels
constexpr int CO = 12;   // head output channels (8 offsets + 4 logits)

static __device__ __forceinline__ float silu_f(float x) { return x / (1.0f + expf(-x)); }

// ---- avg pool by factor F (f32 in, f32 out) -------------------------------
template<int F>
__global__ void pool_kernel(const float* __restrict__ x, float* __restrict__ out,
                            int Ho, int Wo) {
    int idx = blockIdx.x * blockDim.x + threadIdx.x;
    int total = B * C * Ho * Wo;
    if (idx >= total) return;
    int wo = idx % Wo; int t = idx / Wo;
    int ho = t % Ho;   t /= Ho;                 // t = b*C + c
    const float* src = x + ((size_t)t * H + (size_t)ho * F) * W + (size_t)wo * F;
    float s = 0.0f;
#pragma unroll
    for (int dy = 0; dy < F; ++dy)
#pragma unroll
        for (int dx = 0; dx < F; ++dx)
            s += src[dy * W + dx];
    out[idx] = s * (1.0f / (F * F));
}

// ---- fused ds_block: dwconv3 + 1x1 + BN + SiLU ----------------------------
__global__ void fused_ds_kernel(const float* __restrict__ in, const float* __restrict__ dw,
                                const float* __restrict__ pw, const float* __restrict__ g,
                                const float* __restrict__ bb, const float* __restrict__ m,
                                const float* __restrict__ v, float* __restrict__ out,
                                int Hs, int Ws) {
    __shared__ float ws[C * C];        // 1x1 weights
    __shared__ float dws[C * 9];       // depthwise weights
    __shared__ float scale_s[C], shift_s[C];
    int tid = threadIdx.x;
    for (int i = tid; i < C * C; i += blockDim.x) ws[i] = pw[i];
    for (int i = tid; i < C * 9; i += blockDim.x) dws[i] = dw[i];
    if (tid < C) {
        float sc = g[tid] * rsqrtf(v[tid] + 1e-5f);
        scale_s[tid] = sc;
        shift_s[tid] = bb[tid] - m[tid] * sc;
    }
    __syncthreads();
    int HWs = Hs * Ws;
    int idx = blockIdx.x * blockDim.x + tid;
    if (idx >= B * HWs) return;
    int b = idx / HWs, p = idx % HWs;
    int y = p / Ws, x = p % Ws;

    int off[9]; float msk[9];
#pragma unroll
    for (int dy = -1; dy <= 1; ++dy)
#pragma unroll
        for (int dx = -1; dx <= 1; ++dx) {
            int j = (dy + 1) * 3 + (dx + 1);
            int yy = y + dy, xx = x + dx;
            bool ok = (yy >= 0 && yy < Hs && xx >= 0 && xx < Ws);
            int yc = min(max(yy, 0), Hs - 1), xc = min(max(xx, 0), Ws - 1);
            off[j] = yc * Ws + xc;
            msk[j] = ok ? 1.0f : 0.0f;
        }

    const float* src = in + (size_t)b * C * HWs;
    float t[C];
#pragma unroll
    for (int i = 0; i < C; ++i) {
        const float* sc = src + (size_t)i * HWs;
        float s = 0.0f;
#pragma unroll
        for (int j = 0; j < 9; ++j) s += dws[i * 9 + j] * sc[off[j]] * msk[j];
        t[i] = s;
    }
    float* dst = out + (size_t)b * C * HWs + p;
#pragma unroll 4
    for (int o = 0; o < C; ++o) {
        float acc = 0.0f;
#pragma unroll
        for (int i = 0; i < C; ++i) acc += ws[o * C + i] * t[i];
        acc = acc * scale_s[o] + shift_s[o];
        dst[(size_t)o * HWs] = silu_f(acc);
    }
}

// ---- 1x1 conv over C=32 (q projection) ------------------------------------
__global__ void pw_kernel(const float* __restrict__ in, const float* __restrict__ w,
                          float* __restrict__ out, int HWs) {
    __shared__ float ws[C * C];
    int tid = threadIdx.x;
    for (int i = tid; i < C * C; i += blockDim.x) ws[i] = w[i];
    __syncthreads();
    int idx = blockIdx.x * blockDim.x + tid;
    if (idx >= B * HWs) return;
    int b = idx / HWs, p = idx % HWs;
    const float* src = in + (size_t)b * C * HWs + p;
    float xin[C];
#pragma unroll
    for (int i = 0; i < C; ++i) xin[i] = src[(size_t)i * HWs];
    float* dst = out + (size_t)b * C * HWs + p;
#pragma unroll 4
    for (int o = 0; o < C; ++o) {
        float acc = 0.0f;
#pragma unroll
        for (int i = 0; i < C; ++i) acc += ws[o * C + i] * xin[i];
        dst[(size_t)o * HWs] = acc;
    }
}

// ---- fused offset head (3x3 conv + silu + 1x1 + bias + softmax/tanh)
//      + deformable bilinear sampling ---------------------------------------
template<int HC, int WC>
__global__ void head_deform_kernel(const float* __restrict__ q, const float* __restrict__ z,
                                   const float* __restrict__ w1, const float* __restrict__ w2,
                                   const float* __restrict__ b2, float* __restrict__ y) {
    __shared__ float w1s[CH * C * 9];   // 18 KiB
    __shared__ float w2s[CO * CH];
    __shared__ float b2s[CO];
    int tid = threadIdx.x;
    for (int i = tid; i < CH * C * 9; i += blockDim.x) w1s[i] = w1[i];
    for (int i = tid; i < CO * CH; i += blockDim.x) w2s[i] = w2[i];
    if (tid < CO) b2s[tid] = b2[tid];
    __syncthreads();
    int idx = blockIdx.x * blockDim.x + tid;
    if (idx >= B * HW) return;
    int b = idx / HW, p = idx % HW;
    int py = p / W, px = p % W;

    int off[9]; float msk[9];
#pragma unroll
    for (int dy = -1; dy <= 1; ++dy)
#pragma unroll
        for (int dx = -1; dx <= 1; ++dx) {
            int j = (dy + 1) * 3 + (dx + 1);
            int yy = py + dy, xx = px + dx;
            bool ok = (yy >= 0 && yy < H && xx >= 0 && xx < W);
            int yc = min(max(yy, 0), H - 1), xc = min(max(xx, 0), W - 1);
            off[j] = yc * W + xc;
            msk[j] = ok ? 1.0f : 0.0f;
        }

    // 3x3 conv 32->16
    float hid[CH];
#pragma unroll
    for (int o = 0; o < CH; ++o) hid[o] = 0.0f;
    const float* qb = q + (size_t)b * C * HW;
    for (int i = 0; i < C; ++i) {
        const float* sc = qb + (size_t)i * HW;
        float vv[9];
#pragma unroll
        for (int j = 0; j < 9; ++j) vv[j] = sc[off[j]] * msk[j];
#pragma unroll
        for (int o = 0; o < CH; ++o) {
            const float* wp = w1s + (o * C + i) * 9;
            float a = hid[o];
#pragma unroll
            for (int j = 0; j < 9; ++j) a += wp[j] * vv[j];
            hid[o] = a;
        }
    }
#pragma unroll
    for (int o = 0; o < CH; ++o) hid[o] = silu_f(hid[o]);

    // 1x1 conv 16->12 + bias
    float o12[CO];
#pragma unroll
    for (int j = 0; j < CO; ++j) {
        float acc = b2s[j];
#pragma unroll
        for (int i = 0; i < CH; ++i) acc += w2s[j * CH + i] * hid[i];
        o12[j] = acc;
    }

    // softmax over the 4 logits
    float mx = fmaxf(fmaxf(o12[8], o12[9]), fmaxf(o12[10], o12[11]));
    float e[4], se = 0.0f;
#pragma unroll
    for (int k = 0; k < 4; ++k) { e[k] = expf(o12[8 + k] - mx); se += e[k]; }
    float inv = 1.0f / se;

    // base coords in coarse-pixel units
    float xc = (px + 0.5f) * ((float)WC / (float)W) - 0.5f;
    float yc = (py + 0.5f) * ((float)HC / (float)H) - 0.5f;

    float acc[C];
#pragma unroll
    for (int c = 0; c < C; ++c) acc[c] = 0.0f;
    const float* zb = z + (size_t)b * C * HC * WC;
#pragma unroll
    for (int k = 0; k < 4; ++k) {
        float wk = e[k] * inv;
        float ix = fminf(fmaxf(xc + 2.0f * tanhf(o12[2 * k]),     0.0f), (float)(WC - 1));
        float iy = fminf(fmaxf(yc + 2.0f * tanhf(o12[2 * k + 1]), 0.0f), (float)(HC - 1));
        float x0f = floorf(ix), y0f = floorf(iy);
        int x0 = (int)x0f, y0 = (int)y0f;
        int x1 = min(x0 + 1, WC - 1), y1 = min(y0 + 1, HC - 1);
        float wx = ix - x0f, wy = iy - y0f;
        float w00 = (1.0f - wx) * (1.0f - wy) * wk;
        float w01 = wx * (1.0f - wy) * wk;
        float w10 = (1.0f - wx) * wy * wk;
        float w11 = wx * wy * wk;
        int i00 = y0 * WC + x0, i01 = y0 * WC + x1;
        int i10 = y1 * WC + x0, i11 = y1 * WC + x1;
#pragma unroll
        for (int c = 0; c < C; ++c) {
            const float* zc = zb + (size_t)c * HC * WC;
            acc[c] += w00 * zc[i00] + w01 * zc[i01] + w10 * zc[i10] + w11 * zc[i11];
        }
    }
    float* dst = y + (size_t)b * C * HW + p;
#pragma unroll
    for (int c = 0; c < C; ++c) dst[(size_t)c * HW] = acc[c];
}

// ---- per-plane mean (B*C blocks) ------------------------------------------
__global__ void mean_kernel(const float* __restrict__ in, float* __restrict__ dall, int ofs) {
    int plane = blockIdx.x;                     // b*C + c
    const float* src = in + (size_t)plane * HW;
    float s = 0.0f;
    for (int i = threadIdx.x; i < HW; i += blockDim.x) s += src[i];
#pragma unroll
    for (int o = 32; o > 0; o >>= 1) s += __shfl_down(s, o, 64);
    __shared__ float ls[4];
    if ((threadIdx.x & 63) == 0) ls[threadIdx.x >> 6] = s;
    __syncthreads();
    if (threadIdx.x == 0) {
        float t = ls[0] + ls[1] + ls[2] + ls[3];
        int b = plane / C, c = plane % C;
        dall[b * 96 + ofs + c] = t * (1.0f / HW);
    }
}

// ---- gating MLP + softmax -> alpha[B*3] -----------------------------------
__global__ void gate_kernel(const float* __restrict__ dall,
                            const float* __restrict__ w1, const float* __restrict__ b1,
                            const float* __restrict__ w2, const float* __restrict__ b2,
                            float* __restrict__ alpha) {
    __shared__ float hid[B][32];
    int tid = threadIdx.x;                       // 128 threads: b = tid/32, j = tid%32
    int b = tid >> 5, j = tid & 31;
    float a = b1[j];
    for (int k = 0; k < 96; ++k) a += dall[b * 96 + k] * w1[k * 32 + j];
    hid[b][j] = silu_f(a);
    __syncthreads();
    if (j == 0) {
        float lg[3];
#pragma unroll
        for (int t = 0; t < 3; ++t) {
            float acc = b2[t];
            for (int jj = 0; jj < 32; ++jj) acc += hid[b][jj] * w2[jj * 3 + t];
            lg[t] = acc;
        }
        float mx = fmaxf(lg[0], fmaxf(lg[1], lg[2]));
        float e0 = expf(lg[0] - mx), e1 = expf(lg[1] - mx), e2 = expf(lg[2] - mx);
        float inv = 1.0f / (e0 + e1 + e2);
        alpha[b * 3 + 0] = e0 * inv;
        alpha[b * 3 + 1] = e1 * inv;
        alpha[b * 3 + 2] = e2 * inv;
    }
}

// ---- fused mix + final 1x1 conv + residual --------------------------------
__global__ void final_kernel(const float* __restrict__ x,
                             const float* __restrict__ z0, const float* __restrict__ y1,
                             const float* __restrict__ y2, const float* __restrict__ alpha,
                             const float* __restrict__ fw, float* __restrict__ out) {
    __shared__ float ws[C * C];
    for (int i = threadIdx.x; i < C * C; i += blockDim.x) ws[i] = fw[i];
    __syncthreads();
    int idx = blockIdx.x * blockDim.x + threadIdx.x;
    if (idx >= B * HW) return;
    int b = idx / HW, p = idx % HW;
    float a0 = alpha[b * 3], a1 = alpha[b * 3 + 1], a2 = alpha[b * 3 + 2];
    size_t base = (size_t)b * C * HW + p;
    float mix[C];
#pragma unroll
    for (int i = 0; i < C; ++i) {
        size_t e = base + (size_t)i * HW;
        mix[i] = a0 * z0[e] + a1 * y1[e] + a2 * y2[e];
    }
#pragma unroll 4
    for (int o = 0; o < C; ++o) {
        float acc = 0.0f;
#pragma unroll
        for (int i = 0; i < C; ++i) acc += ws[o * C + i] * mix[i];
        size_t e = base + (size_t)o * HW;
        out[e] = acc + x[e];
    }
}

// ---------------------------------------------------------------------------
extern "C" void kernel_launch(void* const* d_in, const int* in_sizes, int n_in,
                              void* d_out, int out_size, void* d_ws, size_t ws_size,
                              hipStream_t stream) {
    const float* x       = (const float*)d_in[0];
    const float* ds_dw[3] = {(const float*)d_in[1],  (const float*)d_in[7],  (const float*)d_in[13]};
    const float* ds_pw[3] = {(const float*)d_in[2],  (const float*)d_in[8],  (const float*)d_in[14]};
    const float* ds_g[3]  = {(const float*)d_in[3],  (const float*)d_in[9],  (const float*)d_in[15]};
    const float* ds_b[3]  = {(const float*)d_in[4],  (const float*)d_in[10], (const float*)d_in[16]};
    const float* ds_m[3]  = {(const float*)d_in[5],  (const float*)d_in[11], (const float*)d_in[17]};
    const float* ds_v[3]  = {(const float*)d_in[6],  (const float*)d_in[12], (const float*)d_in[18]};
    const float* qproj_w = (const float*)d_in[19];
    const float* h1_w1   = (const float*)d_in[20];
    const float* h1_w2   = (const float*)d_in[21];
    const float* h1_b2   = (const float*)d_in[22];
    const float* h2_w1   = (const float*)d_in[23];
    const float* h2_w2   = (const float*)d_in[24];
    const float* h2_b2   = (const float*)d_in[25];
    const float* r_w1    = (const float*)d_in[26];
    const float* r_b1    = (const float*)d_in[27];
    const float* r_w2    = (const float*)d_in[28];
    const float* r_b2    = (const float*)d_in[29];
    const float* final_w = (const float*)d_in[30];
    float* out = (float*)d_out;

    constexpr size_t N0 = (size_t)B * C * HW;    // 8388608
    constexpr size_t N1 = (size_t)B * C * HW1;   // 2097152
    constexpr size_t N2 = (size_t)B * C * HW2;   // 524288

    float* w  = (float*)d_ws;
    float* z0  = w; w += N0;
    float* q   = w; w += N0;
    float* y1  = w; w += N0;     // aliases s1 before deform
    float* y2  = w; w += N0;     // aliases s2 before deform
    float* z1  = w; w += N1;
    float* z2  = w; w += N2;
    float* dall  = w; w += 512;
    float* alpha = w; w += 16;
    (void)ws_size; (void)in_sizes; (void)n_in; (void)out_size;

    const int T = 256;
    auto g = [](size_t n, int t) { return (int)((n + t - 1) / t); };

    float* s1 = y1;
    float* s2 = y2;

    // pools
    pool_kernel<2><<<g(N1, T), T, 0, stream>>>(x, s1, H1, W1);
    pool_kernel<4><<<g(N2, T), T, 0, stream>>>(x, s2, H2, W2);

    // ds blocks (fused dwconv + 1x1 + bn + silu)
    fused_ds_kernel<<<g((size_t)B * HW, T), T, 0, stream>>>(x,  ds_dw[0], ds_pw[0], ds_g[0], ds_b[0], ds_m[0], ds_v[0], z0, H, W);
    fused_ds_kernel<<<g((size_t)B * HW1, T), T, 0, stream>>>(s1, ds_dw[1], ds_pw[1], ds_g[1], ds_b[1], ds_m[1], ds_v[1], z1, H1, W1);
    fused_ds_kernel<<<g((size_t)B * HW2, T), T, 0, stream>>>(s2, ds_dw[2], ds_pw[2], ds_g[2], ds_b[2], ds_m[2], ds_v[2], z2, H2, W2);

    // q projection
    pw_kernel<<<g((size_t)B * HW, T), T, 0, stream>>>(z0, qproj_w, q, HW);

    // heads + deformable sampling (fused)
    head_deform_kernel<H1, W1><<<g((size_t)B * HW, T), T, 0, stream>>>(q, z1, h1_w1, h1_w2, h1_b2, y1);
    head_deform_kernel<H2, W2><<<g((size_t)B * HW, T), T, 0, stream>>>(q, z2, h2_w1, h2_w2, h2_b2, y2);

    // descriptors + gate
    mean_kernel<<<B * C, T, 0, stream>>>(z0, dall, 0);
    mean_kernel<<<B * C, T, 0, stream>>>(y1, dall, 32);
    mean_kernel<<<B * C, T, 0, stream>>>(y2, dall, 64);
    gate_kernel<<<1, 128, 0, stream>>>(dall, r_w1, r_b1, r_w2, r_b2, alpha);

    // fused mix + final conv + residual
    final_kernel<<<g((size_t)B * HW, T), T, 0, stream>>>(x, z0, y1, y2, alpha, final_w, out);
}

// Round 3
// 599.913 us; speedup vs baseline: 2.7508x; 2.7508x over previous
//
#include <hip/hip_runtime.h>
#include <math.h>

// ---------------------------------------------------------------------------
// CSDM pipeline on MI355X. fp32 in/out, fp32/bf16 intermediates in d_ws.
// B=4, C=32, H=W=256. LDS-tiled stencils, channel-last coarse maps for the
// deformable gather, both offset heads fused into one kernel.
// ---------------------------------------------------------------------------

constexpr int B = 4, C = 32, H = 256, W = 256;
constexpr int HW = H * W;
constexpr int H1 = 128, W1 = 128, HW1 = H1 * W1;
constexpr int H2 = 64,  W2 = 64,  HW2 = H2 * W2;
constexpr int CH = 16;   // head hidden channels
constexpr int CO = 12;   // head output channels
constexpr int TILE = 16; // spatial tile edge
constexpr int HALO = 18; // TILE + 2
constexpr int TAREA = HALO * HALO;   // 324

typedef unsigned short ushort_t;

static __device__ __forceinline__ float fast_rcp(float x) { return __builtin_amdgcn_rcpf(x); }
static __device__ __forceinline__ float silu_f(float x) { return x * fast_rcp(1.0f + __expf(-x)); }
static __device__ __forceinline__ float tanh_f(float x) {
    float xc = fminf(fmaxf(x, -15.0f), 15.0f);
    float e = __expf(2.0f * xc);
    return (e - 1.0f) * fast_rcp(e + 1.0f);
}
static __device__ __forceinline__ ushort_t f2b(float f) {   // fp32 -> bf16 RNE
    unsigned u = __float_as_uint(f);
    return (ushort_t)((u + 0x7fffu + ((u >> 16) & 1u)) >> 16);
}
static __device__ __forceinline__ float b2f(ushort_t u) {
    return __uint_as_float(((unsigned)u) << 16);
}

// ---- avg pool by factor F -------------------------------------------------
template<int F>
__global__ void pool_kernel(const float* __restrict__ x, float* __restrict__ out,
                            int Ho, int Wo) {
    int idx = blockIdx.x * blockDim.x + threadIdx.x;
    int total = B * C * Ho * Wo;
    if (idx >= total) return;
    int wo = idx % Wo; int t = idx / Wo;
    int ho = t % Ho;   t /= Ho;
    const float* src = x + ((size_t)t * H + (size_t)ho * F) * W + (size_t)wo * F;
    float s = 0.0f;
#pragma unroll
    for (int dy = 0; dy < F; ++dy)
#pragma unroll
        for (int dx = 0; dx < F; ++dx)
            s += src[dy * W + dx];
    out[idx] = s * (1.0f / (F * F));
}

// ---- fused ds_block: LDS-tiled dwconv3 + 1x1 + BN + SiLU (+ q-proj) -------
// CHLAST: write z channel-last [b][p][c]; else plane [b][c][p].
// WITHQ : also compute q = qw*z and store bf16 plane layout.
template<bool CHLAST, bool WITHQ>
__global__ __launch_bounds__(256, 4) void fused_ds_kernel(
        const float* __restrict__ in, const float* __restrict__ dw,
        const float* __restrict__ pw, const float* __restrict__ g,
        const float* __restrict__ bb, const float* __restrict__ m,
        const float* __restrict__ v, const float* __restrict__ qw,
        float* __restrict__ out, ushort_t* __restrict__ qout,
        int Hs, int Ws, int tilesX) {
    __shared__ ushort_t tile[C * TAREA];      // 20736 B
    __shared__ float dws[C * 9];
    __shared__ float pws[C * C];
    __shared__ float qws[WITHQ ? C * C : 1];
    __shared__ float scale_s[C], shift_s[C];
    int tid = threadIdx.x;
    int b = blockIdx.y;
    int HWs = Hs * Ws;
    int ox = (blockIdx.x % tilesX) * TILE;
    int oy = (blockIdx.x / tilesX) * TILE;

    for (int i = tid; i < C * 9; i += 256) dws[i] = dw[i];
    for (int i = tid; i < C * C; i += 256) pws[i] = pw[i];
    if (WITHQ) for (int i = tid; i < C * C; i += 256) qws[i] = qw[i];
    if (tid < C) {
        float sc = g[tid] * rsqrtf(v[tid] + 1e-5f);
        scale_s[tid] = sc;
        shift_s[tid] = bb[tid] - m[tid] * sc;
    }
    const float* src = in + (size_t)b * C * HWs;
    for (int i = tid; i < C * TAREA; i += 256) {
        int c = i / TAREA, r = i - c * TAREA;
        int yy = r / HALO, xx = r - yy * HALO;
        int gy = oy - 1 + yy, gx = ox - 1 + xx;
        float val = 0.0f;
        if (gy >= 0 && gy < Hs && gx >= 0 && gx < Ws)
            val = src[(size_t)c * HWs + gy * Ws + gx];
        tile[i] = f2b(val);
    }
    __syncthreads();

    int tx = tid & 15, ty = tid >> 4;
    float t[C];
#pragma unroll
    for (int c = 0; c < C; ++c) {
        const ushort_t* tp = tile + c * TAREA + ty * HALO + tx;
        float s = 0.0f;
#pragma unroll
        for (int jy = 0; jy < 3; ++jy)
#pragma unroll
            for (int jx = 0; jx < 3; ++jx)
                s += dws[c * 9 + jy * 3 + jx] * b2f(tp[jy * HALO + jx]);
        t[c] = s;
    }
    int px = ox + tx, py = oy + ty;
    int p = py * Ws + px;
    float zo[C];
#pragma unroll 4
    for (int o = 0; o < C; ++o) {
        float acc = 0.0f;
#pragma unroll
        for (int i = 0; i < C; ++i) acc += pws[o * C + i] * t[i];
        zo[o] = silu_f(acc * scale_s[o] + shift_s[o]);
    }
    if (CHLAST) {
        float4* dst = (float4*)(out + ((size_t)b * HWs + p) * C);
#pragma unroll
        for (int o4 = 0; o4 < C / 4; ++o4)
            dst[o4] = make_float4(zo[4 * o4], zo[4 * o4 + 1], zo[4 * o4 + 2], zo[4 * o4 + 3]);
    } else {
        float* dst = out + (size_t)b * C * HWs + p;
#pragma unroll
        for (int o = 0; o < C; ++o) dst[(size_t)o * HWs] = zo[o];
    }
    if (WITHQ) {
        ushort_t* qd = qout + (size_t)b * C * HWs + p;
#pragma unroll 4
        for (int o = 0; o < C; ++o) {
            float acc = 0.0f;
#pragma unroll
            for (int i = 0; i < C; ++i) acc += qws[o * C + i] * zo[i];
            qd[(size_t)o * HWs] = f2b(acc);
        }
    }
}

// ---- one head: 3x3 conv (from LDS tile) + silu + 1x1 + softmax/tanh
//      + deform gather from channel-last z ---------------------------------
template<int HC, int WC>
static __device__ __forceinline__ void head_one(
        const ushort_t* tile, const float* w1s, const float* w2s, const float* b2s,
        const float* __restrict__ z, float* __restrict__ y,
        int b, int px, int py, int tx, int ty) {
    float hid[CH];
#pragma unroll
    for (int o = 0; o < CH; ++o) hid[o] = 0.0f;
#pragma unroll 2
    for (int i = 0; i < C; ++i) {
        const ushort_t* tp = tile + i * TAREA + ty * HALO + tx;
        float vv[9];
#pragma unroll
        for (int jy = 0; jy < 3; ++jy)
#pragma unroll
            for (int jx = 0; jx < 3; ++jx)
                vv[jy * 3 + jx] = b2f(tp[jy * HALO + jx]);
#pragma unroll
        for (int o = 0; o < CH; ++o) {
            const float* wp = w1s + (o * C + i) * 9;
            float a = hid[o];
#pragma unroll
            for (int j = 0; j < 9; ++j) a += wp[j] * vv[j];
            hid[o] = a;
        }
    }
#pragma unroll
    for (int o = 0; o < CH; ++o) hid[o] = silu_f(hid[o]);

    float o12[CO];
#pragma unroll
    for (int j = 0; j < CO; ++j) {
        float a = b2s[j];
#pragma unroll
        for (int i = 0; i < CH; ++i) a += w2s[j * CH + i] * hid[i];
        o12[j] = a;
    }
    float mx = fmaxf(fmaxf(o12[8], o12[9]), fmaxf(o12[10], o12[11]));
    float e0 = __expf(o12[8] - mx), e1 = __expf(o12[9] - mx);
    float e2 = __expf(o12[10] - mx), e3 = __expf(o12[11] - mx);
    float inv = fast_rcp(e0 + e1 + e2 + e3);
    float wk4[4] = {e0 * inv, e1 * inv, e2 * inv, e3 * inv};

    float xc = (px + 0.5f) * ((float)WC / (float)W) - 0.5f;
    float yc = (py + 0.5f) * ((float)HC / (float)H) - 0.5f;

    float acc[C];
#pragma unroll
    for (int c = 0; c < C; ++c) acc[c] = 0.0f;
    const float* zb = z + (size_t)b * HC * WC * C;
#pragma unroll
    for (int k = 0; k < 4; ++k) {
        float ix = fminf(fmaxf(xc + 2.0f * tanh_f(o12[2 * k]),     0.0f), (float)(WC - 1));
        float iy = fminf(fmaxf(yc + 2.0f * tanh_f(o12[2 * k + 1]), 0.0f), (float)(HC - 1));
        float x0f = floorf(ix), y0f = floorf(iy);
        int x0 = (int)x0f, y0 = (int)y0f;
        int x1 = min(x0 + 1, WC - 1), y1 = min(y0 + 1, HC - 1);
        float wx = ix - x0f, wy = iy - y0f;
        float wk = wk4[k];
        float w00 = (1.0f - wx) * (1.0f - wy) * wk;
        float w01 = wx * (1.0f - wy) * wk;
        float w10 = (1.0f - wx) * wy * wk;
        float w11 = wx * wy * wk;
        const float4* p00 = (const float4*)(zb + (size_t)(y0 * WC + x0) * C);
        const float4* p01 = (const float4*)(zb + (size_t)(y0 * WC + x1) * C);
        const float4* p10 = (const float4*)(zb + (size_t)(y1 * WC + x0) * C);
        const float4* p11 = (const float4*)(zb + (size_t)(y1 * WC + x1) * C);
#pragma unroll
        for (int c4 = 0; c4 < C / 4; ++c4) {
            float4 a = p00[c4], bq = p01[c4], cq = p10[c4], dq = p11[c4];
            acc[4 * c4 + 0] += w00 * a.x + w01 * bq.x + w10 * cq.x + w11 * dq.x;
            acc[4 * c4 + 1] += w00 * a.y + w01 * bq.y + w10 * cq.y + w11 * dq.y;
            acc[4 * c4 + 2] += w00 * a.z + w01 * bq.z + w10 * cq.z + w11 * dq.z;
            acc[4 * c4 + 3] += w00 * a.w + w01 * bq.w + w10 * cq.w + w11 * dq.w;
        }
    }
    float* dst = y + (size_t)b * C * HW + py * W + px;
#pragma unroll
    for (int c = 0; c < C; ++c) dst[(size_t)c * HW] = acc[c];
}

// ---- both heads fused, sharing the staged q tile --------------------------
__global__ __launch_bounds__(256, 4) void head_deform2_kernel(
        const ushort_t* __restrict__ q, const float* __restrict__ z1,
        const float* __restrict__ z2,
        const float* __restrict__ w1a, const float* __restrict__ w2a, const float* __restrict__ b2a,
        const float* __restrict__ w1b, const float* __restrict__ w2b, const float* __restrict__ b2b,
        float* __restrict__ y1, float* __restrict__ y2) {
    __shared__ ushort_t tile[C * TAREA];        // 20736 B
    __shared__ float w1s[CH * C * 9];           // 18432 B
    __shared__ float w2s[CO * CH];
    __shared__ float b2s[CO];
    int tid = threadIdx.x, b = blockIdx.y;
    int ox = (blockIdx.x & 15) * TILE, oy = (blockIdx.x >> 4) * TILE;
    const ushort_t* src = q + (size_t)b * C * HW;
    for (int i = tid; i < C * TAREA; i += 256) {
        int c = i / TAREA, r = i - c * TAREA;
        int yy = r / HALO, xx = r - yy * HALO;
        int gy = oy - 1 + yy, gx = ox - 1 + xx;
        ushort_t val = 0;
        if (gy >= 0 && gy < H && gx >= 0 && gx < W)
            val = src[(size_t)c * HW + gy * W + gx];
        tile[i] = val;
    }
    for (int i = tid; i < CH * C * 9; i += 256) w1s[i] = w1a[i];
    for (int i = tid; i < CO * CH; i += 256) w2s[i] = w2a[i];
    if (tid < CO) b2s[tid] = b2a[tid];
    __syncthreads();
    int tx = tid & 15, ty = tid >> 4;
    head_one<H1, W1>(tile, w1s, w2s, b2s, z1, y1, b, ox + tx, oy + ty, tx, ty);
    __syncthreads();
    for (int i = tid; i < CH * C * 9; i += 256) w1s[i] = w1b[i];
    for (int i = tid; i < CO * CH; i += 256) w2s[i] = w2b[i];
    if (tid < CO) b2s[tid] = b2b[tid];
    __syncthreads();
    head_one<H2, W2>(tile, w1s, w2s, b2s, z2, y2, b, ox + tx, oy + ty, tx, ty);
}

// ---- merged per-plane means (384 blocks) ----------------------------------
__global__ void mean3_kernel(const float* __restrict__ z0, const float* __restrict__ y1,
                             const float* __restrict__ y2, float* __restrict__ dall) {
    int id = blockIdx.x;             // 0..383
    int srcI = id >> 7, plane = id & 127;
    const float* base = (srcI == 0) ? z0 : (srcI == 1 ? y1 : y2);
    const float* src = base + (size_t)plane * HW;
    float s = 0.0f;
    for (int i = threadIdx.x; i < HW; i += blockDim.x) s += src[i];
#pragma unroll
    for (int o = 32; o > 0; o >>= 1) s += __shfl_down(s, o, 64);
    __shared__ float ls[4];
    if ((threadIdx.x & 63) == 0) ls[threadIdx.x >> 6] = s;
    __syncthreads();
    if (threadIdx.x == 0) {
        float t = ls[0] + ls[1] + ls[2] + ls[3];
        int b = plane >> 5, c = plane & 31;
        dall[b * 96 + srcI * 32 + c] = t * (1.0f / HW);
    }
}

// ---- gating MLP + softmax -> alpha[B*3] -----------------------------------
__global__ void gate_kernel(const float* __restrict__ dall,
                            const float* __restrict__ w1, const float* __restrict__ b1,
                            const float* __restrict__ w2, const float* __restrict__ b2,
                            float* __restrict__ alpha) {
    __shared__ float hid[B][32];
    int tid = threadIdx.x;
    int b = tid >> 5, j = tid & 31;
    float a = b1[j];
    for (int k = 0; k < 96; ++k) a += dall[b * 96 + k] * w1[k * 32 + j];
    hid[b][j] = silu_f(a);
    __syncthreads();
    if (j == 0) {
        float lg[3];
#pragma unroll
        for (int t = 0; t < 3; ++t) {
            float acc = b2[t];
            for (int jj = 0; jj < 32; ++jj) acc += hid[b][jj] * w2[jj * 3 + t];
            lg[t] = acc;
        }
        float mx = fmaxf(lg[0], fmaxf(lg[1], lg[2]));
        float e0 = __expf(lg[0] - mx), e1 = __expf(lg[1] - mx), e2 = __expf(lg[2] - mx);
        float inv = fast_rcp(e0 + e1 + e2);
        alpha[b * 3 + 0] = e0 * inv;
        alpha[b * 3 + 1] = e1 * inv;
        alpha[b * 3 + 2] = e2 * inv;
    }
}

// ---- fused mix + final 1x1 conv + residual --------------------------------
__global__ __launch_bounds__(256, 4) void final_kernel(
        const float* __restrict__ x,
        const float* __restrict__ z0, const float* __restrict__ y1,
        const float* __restrict__ y2, const float* __restrict__ alpha,
        const float* __restrict__ fw, float* __restrict__ out) {
    __shared__ float ws[C * C];
    for (int i = threadIdx.x; i < C * C; i += blockDim.x) ws[i] = fw[i];
    __syncthreads();
    int idx = blockIdx.x * blockDim.x + threadIdx.x;
    if (idx >= B * HW) return;
    int b = idx / HW, p = idx % HW;
    float a0 = alpha[b * 3], a1 = alpha[b * 3 + 1], a2 = alpha[b * 3 + 2];
    size_t base = (size_t)b * C * HW + p;
    float mix[C];
#pragma unroll
    for (int i = 0; i < C; ++i) {
        size_t e = base + (size_t)i * HW;
        mix[i] = a0 * z0[e] + a1 * y1[e] + a2 * y2[e];
    }
#pragma unroll 4
    for (int o = 0; o < C; ++o) {
        float acc = 0.0f;
#pragma unroll
        for (int i = 0; i < C; ++i) acc += ws[o * C + i] * mix[i];
        size_t e = base + (size_t)o * HW;
        out[e] = acc + x[e];
    }
}

// ---------------------------------------------------------------------------
extern "C" void kernel_launch(void* const* d_in, const int* in_sizes, int n_in,
                              void* d_out, int out_size, void* d_ws, size_t ws_size,
                              hipStream_t stream) {
    const float* x       = (const float*)d_in[0];
    const float* ds_dw[3] = {(const float*)d_in[1],  (const float*)d_in[7],  (const float*)d_in[13]};
    const float* ds_pw[3] = {(const float*)d_in[2],  (const float*)d_in[8],  (const float*)d_in[14]};
    const float* ds_g[3]  = {(const float*)d_in[3],  (const float*)d_in[9],  (const float*)d_in[15]};
    const float* ds_b[3]  = {(const float*)d_in[4],  (const float*)d_in[10], (const float*)d_in[16]};
    const float* ds_m[3]  = {(const float*)d_in[5],  (const float*)d_in[11], (const float*)d_in[17]};
    const float* ds_v[3]  = {(const float*)d_in[6],  (const float*)d_in[12], (const float*)d_in[18]};
    const float* qproj_w = (const float*)d_in[19];
    const float* h1_w1   = (const float*)d_in[20];
    const float* h1_w2   = (const float*)d_in[21];
    const float* h1_b2   = (const float*)d_in[22];
    const float* h2_w1   = (const float*)d_in[23];
    const float* h2_w2   = (const float*)d_in[24];
    const float* h2_b2   = (const float*)d_in[25];
    const float* r_w1    = (const float*)d_in[26];
    const float* r_b1    = (const float*)d_in[27];
    const float* r_w2    = (const float*)d_in[28];
    const float* r_b2    = (const float*)d_in[29];
    const float* final_w = (const float*)d_in[30];
    float* out = (float*)d_out;

    constexpr size_t N0 = (size_t)B * C * HW;
    constexpr size_t N1 = (size_t)B * C * HW1;
    constexpr size_t N2 = (size_t)B * C * HW2;

    float* w = (float*)d_ws;
    float* z0   = w; w += N0;
    float* y1   = w; w += N0;
    float* y2   = w; w += N0;
    float* z1cl = w; w += N1;      // channel-last
    float* z2cl = w; w += N2;      // channel-last
    float* s1   = w; w += N1;
    float* s2   = w; w += N2;
    ushort_t* qb = (ushort_t*)w; w += N0 / 2;   // q as bf16
    float* dall  = w; w += 512;
    float* alpha = w; w += 16;
    (void)ws_size; (void)in_sizes; (void)n_in; (void)out_size;

    const int T = 256;
    auto g = [](size_t n, int t) { return (int)((n + t - 1) / t); };

    // pools
    pool_kernel<2><<<g(N1, T), T, 0, stream>>>(x, s1, H1, W1);
    pool_kernel<4><<<g(N2, T), T, 0, stream>>>(x, s2, H2, W2);

    // ds blocks (tiled); ds0 also emits q (bf16)
    fused_ds_kernel<false, true><<<dim3((H / TILE) * (W / TILE), B), T, 0, stream>>>(
        x, ds_dw[0], ds_pw[0], ds_g[0], ds_b[0], ds_m[0], ds_v[0], qproj_w,
        z0, qb, H, W, W / TILE);
    fused_ds_kernel<true, false><<<dim3((H1 / TILE) * (W1 / TILE), B), T, 0, stream>>>(
        s1, ds_dw[1], ds_pw[1], ds_g[1], ds_b[1], ds_m[1], ds_v[1], nullptr,
        z1cl, nullptr, H1, W1, W1 / TILE);
    fused_ds_kernel<true, false><<<dim3((H2 / TILE) * (W2 / TILE), B), T, 0, stream>>>(
        s2, ds_dw[2], ds_pw[2], ds_g[2], ds_b[2], ds_m[2], ds_v[2], nullptr,
        z2cl, nullptr, H2, W2, W2 / TILE);

    // both heads + deformable sampling
    head_deform2_kernel<<<dim3((H / TILE) * (W / TILE), B), T, 0, stream>>>(
        qb, z1cl, z2cl, h1_w1, h1_w2, h1_b2, h2_w1, h2_w2, h2_b2, y1, y2);

    // descriptors + gate
    mean3_kernel<<<384, T, 0, stream>>>(z0, y1, y2, dall);
    gate_kernel<<<1, 128, 0, stream>>>(dall, r_w1, r_b1, r_w2, r_b2, alpha);

    // fused mix + final conv + residual
    final_kernel<<<g((size_t)B * HW, T), T, 0, stream>>>(x, z0, y1, y2, alpha, final_w, out);
}

// Round 4
// 502.229 us; speedup vs baseline: 3.2858x; 1.1945x over previous
//
#include <hip/hip_runtime.h>
#include <math.h>

// ---------------------------------------------------------------------------
// CSDM pipeline on MI355X. fp32 in/out, fp32/bf16 intermediates in d_ws.
// B=4, C=32, H=W=256. LDS-tiled stencils; head 3x3 conv runs on MFMA
// (v_mfma_f32_16x16x32_bf16) with q stored channel-last zero-padded bf16.
// ---------------------------------------------------------------------------

constexpr int B = 4, C = 32, H = 256, W = 256;
constexpr int HW = H * W;
constexpr int H1 = 128, W1 = 128, HW1 = H1 * W1;
constexpr int H2 = 64,  W2 = 64,  HW2 = H2 * W2;
constexpr int CH = 16;   // head hidden channels
constexpr int CO = 12;   // head output channels
constexpr int TILE = 16;
constexpr int HALO = 18;
constexpr int TAREA = HALO * HALO;   // 324
constexpr int WP = 258;              // padded q edge

typedef unsigned short ushort_t;
typedef __attribute__((ext_vector_type(8))) short bf16x8;
typedef __attribute__((ext_vector_type(4))) float f32x4;

static __device__ __forceinline__ float fast_rcp(float x) { return __builtin_amdgcn_rcpf(x); }
static __device__ __forceinline__ float silu_f(float x) { return x * fast_rcp(1.0f + __expf(-x)); }
static __device__ __forceinline__ float tanh_f(float x) {
    float xc = fminf(fmaxf(x, -15.0f), 15.0f);
    float e = __expf(2.0f * xc);
    return (e - 1.0f) * fast_rcp(e + 1.0f);
}
static __device__ __forceinline__ ushort_t f2b(float f) {   // fp32 -> bf16 RNE
    unsigned u = __float_as_uint(f);
    return (ushort_t)((u + 0x7fffu + ((u >> 16) & 1u)) >> 16);
}
static __device__ __forceinline__ float b2f(ushort_t u) {
    return __uint_as_float(((unsigned)u) << 16);
}

// ---- avg pool by factor F -------------------------------------------------
template<int F>
__global__ void pool_kernel(const float* __restrict__ x, float* __restrict__ out,
                            int Ho, int Wo) {
    int idx = blockIdx.x * blockDim.x + threadIdx.x;
    int total = B * C * Ho * Wo;
    if (idx >= total) return;
    int wo = idx % Wo; int t = idx / Wo;
    int ho = t % Ho;   t /= Ho;
    const float* src = x + ((size_t)t * H + (size_t)ho * F) * W + (size_t)wo * F;
    float s = 0.0f;
#pragma unroll
    for (int dy = 0; dy < F; ++dy)
#pragma unroll
        for (int dx = 0; dx < F; ++dx)
            s += src[dy * W + dx];
    out[idx] = s * (1.0f / (F * F));
}

// ---- zero the 1-px border of padded channel-last q ------------------------
__global__ void qpad_border_kernel(ushort_t* __restrict__ qpad) {
    int i = blockIdx.x * blockDim.x + threadIdx.x;
    if (i >= 4 * 1028) return;
    int b = i / 1028, r = i % 1028;
    int y, x;
    if (r < 258)      { y = 0;           x = r; }
    else if (r < 516) { y = 257;         x = r - 258; }
    else if (r < 772) { y = r - 516 + 1; x = 0; }
    else              { y = r - 772 + 1; x = 257; }
    uint4 z4 = {0, 0, 0, 0};
    uint4* p = (uint4*)(qpad + (((size_t)b * WP + y) * WP + x) * 32);
    p[0] = z4; p[1] = z4; p[2] = z4; p[3] = z4;
}

// ---- fused ds_block: LDS-tiled dwconv3 + 1x1 + BN + SiLU (+ q-proj) -------
// CHLAST: write z channel-last [b][p][c]; else plane [b][c][p].
// WITHQ : also compute q = qw*z, store bf16 channel-last into padded qpad.
template<bool CHLAST, bool WITHQ>
__global__ __launch_bounds__(256, 4) void fused_ds_kernel(
        const float* __restrict__ in, const float* __restrict__ dw,
        const float* __restrict__ pw, const float* __restrict__ g,
        const float* __restrict__ bb, const float* __restrict__ m,
        const float* __restrict__ v, const float* __restrict__ qw,
        float* __restrict__ out, ushort_t* __restrict__ qout,
        int Hs, int Ws, int tilesX) {
    __shared__ ushort_t tile[C * TAREA];
    __shared__ float dws[C * 9];
    __shared__ float pws[C * C];
    __shared__ float qws[WITHQ ? C * C : 1];
    __shared__ float scale_s[C], shift_s[C];
    int tid = threadIdx.x;
    int b = blockIdx.y;
    int HWs = Hs * Ws;
    int ox = (blockIdx.x % tilesX) * TILE;
    int oy = (blockIdx.x / tilesX) * TILE;

    for (int i = tid; i < C * 9; i += 256) dws[i] = dw[i];
    for (int i = tid; i < C * C; i += 256) pws[i] = pw[i];
    if (WITHQ) for (int i = tid; i < C * C; i += 256) qws[i] = qw[i];
    if (tid < C) {
        float sc = g[tid] * rsqrtf(v[tid] + 1e-5f);
        scale_s[tid] = sc;
        shift_s[tid] = bb[tid] - m[tid] * sc;
    }
    const float* src = in + (size_t)b * C * HWs;
    for (int i = tid; i < C * TAREA; i += 256) {
        int c = i / TAREA, r = i - c * TAREA;
        int yy = r / HALO, xx = r - yy * HALO;
        int gy = oy - 1 + yy, gx = ox - 1 + xx;
        float val = 0.0f;
        if (gy >= 0 && gy < Hs && gx >= 0 && gx < Ws)
            val = src[(size_t)c * HWs + gy * Ws + gx];
        tile[i] = f2b(val);
    }
    __syncthreads();

    int tx = tid & 15, ty = tid >> 4;
    float t[C];
#pragma unroll
    for (int c = 0; c < C; ++c) {
        const ushort_t* tp = tile + c * TAREA + ty * HALO + tx;
        float s = 0.0f;
#pragma unroll
        for (int jy = 0; jy < 3; ++jy)
#pragma unroll
            for (int jx = 0; jx < 3; ++jx)
                s += dws[c * 9 + jy * 3 + jx] * b2f(tp[jy * HALO + jx]);
        t[c] = s;
    }
    int px = ox + tx, py = oy + ty;
    int p = py * Ws + px;
    float zo[C];
#pragma unroll 4
    for (int o = 0; o < C; ++o) {
        float acc = 0.0f;
#pragma unroll
        for (int i = 0; i < C; ++i) acc += pws[o * C + i] * t[i];
        zo[o] = silu_f(acc * scale_s[o] + shift_s[o]);
    }
    if (CHLAST) {
        float4* dst = (float4*)(out + ((size_t)b * HWs + p) * C);
#pragma unroll
        for (int o4 = 0; o4 < C / 4; ++o4)
            dst[o4] = make_float4(zo[4 * o4], zo[4 * o4 + 1], zo[4 * o4 + 2], zo[4 * o4 + 3]);
    } else {
        float* dst = out + (size_t)b * C * HWs + p;
#pragma unroll
        for (int o = 0; o < C; ++o) dst[(size_t)o * HWs] = zo[o];
    }
    if (WITHQ) {
        float qv[C];
#pragma unroll 4
        for (int o = 0; o < C; ++o) {
            float acc = 0.0f;
#pragma unroll
            for (int i = 0; i < C; ++i) acc += qws[o * C + i] * zo[i];
            qv[o] = acc;
        }
        // pack 32 bf16 -> 16 uints -> 4 uint4 stores, channel-last padded
        unsigned up[16];
#pragma unroll
        for (int j = 0; j < 16; ++j)
            up[j] = (unsigned)f2b(qv[2 * j]) | ((unsigned)f2b(qv[2 * j + 1]) << 16);
        uint4* qd = (uint4*)(qout + (((size_t)b * WP + py + 1) * WP + px + 1) * 32);
#pragma unroll
        for (int j = 0; j < 4; ++j)
            qd[j] = make_uint4(up[4 * j], up[4 * j + 1], up[4 * j + 2], up[4 * j + 3]);
    }
}

// ---- deform tail: silu'd hid -> 1x1 -> softmax/tanh -> bilinear gather ----
template<int HC, int WC>
static __device__ __forceinline__ void head_tail(
        const float* hid, const float* w2s, const float* b2s,
        const float* __restrict__ z, float* __restrict__ y,
        int b, int px, int py) {
    float o12[CO];
#pragma unroll
    for (int j = 0; j < CO; ++j) {
        float a = b2s[j];
#pragma unroll
        for (int i = 0; i < CH; ++i) a += w2s[j * CH + i] * hid[i];
        o12[j] = a;
    }
    float mx = fmaxf(fmaxf(o12[8], o12[9]), fmaxf(o12[10], o12[11]));
    float e0 = __expf(o12[8] - mx), e1 = __expf(o12[9] - mx);
    float e2 = __expf(o12[10] - mx), e3 = __expf(o12[11] - mx);
    float inv = fast_rcp(e0 + e1 + e2 + e3);
    float wk4[4] = {e0 * inv, e1 * inv, e2 * inv, e3 * inv};

    float xc = (px + 0.5f) * ((float)WC / (float)W) - 0.5f;
    float yc = (py + 0.5f) * ((float)HC / (float)H) - 0.5f;

    float acc[C];
#pragma unroll
    for (int c = 0; c < C; ++c) acc[c] = 0.0f;
    const float* zb = z + (size_t)b * HC * WC * C;
#pragma unroll
    for (int k = 0; k < 4; ++k) {
        float ix = fminf(fmaxf(xc + 2.0f * tanh_f(o12[2 * k]),     0.0f), (float)(WC - 1));
        float iy = fminf(fmaxf(yc + 2.0f * tanh_f(o12[2 * k + 1]), 0.0f), (float)(HC - 1));
        float x0f = floorf(ix), y0f = floorf(iy);
        int x0 = (int)x0f, y0 = (int)y0f;
        int x1 = min(x0 + 1, WC - 1), y1 = min(y0 + 1, HC - 1);
        float wx = ix - x0f, wy = iy - y0f;
        float wk = wk4[k];
        float w00 = (1.0f - wx) * (1.0f - wy) * wk;
        float w01 = wx * (1.0f - wy) * wk;
        float w10 = (1.0f - wx) * wy * wk;
        float w11 = wx * wy * wk;
        const float4* p00 = (const float4*)(zb + (size_t)(y0 * WC + x0) * C);
        const float4* p01 = (const float4*)(zb + (size_t)(y0 * WC + x1) * C);
        const float4* p10 = (const float4*)(zb + (size_t)(y1 * WC + x0) * C);
        const float4* p11 = (const float4*)(zb + (size_t)(y1 * WC + x1) * C);
#pragma unroll
        for (int c4 = 0; c4 < C / 4; ++c4) {
            float4 a = p00[c4], bq = p01[c4], cq = p10[c4], dq = p11[c4];
            acc[4 * c4 + 0] += w00 * a.x + w01 * bq.x + w10 * cq.x + w11 * dq.x;
            acc[4 * c4 + 1] += w00 * a.y + w01 * bq.y + w10 * cq.y + w11 * dq.y;
            acc[4 * c4 + 2] += w00 * a.z + w01 * bq.z + w10 * cq.z + w11 * dq.z;
            acc[4 * c4 + 3] += w00 * a.w + w01 * bq.w + w10 * cq.w + w11 * dq.w;
        }
    }
    float* dst = y + (size_t)b * C * HW + py * W + px;
#pragma unroll
    for (int c = 0; c < C; ++c) dst[(size_t)c * HW] = acc[c];
}

// ---- both heads: MFMA 3x3 conv + scalar deform tail -----------------------
// tile: channel-last bf16 [18][18][32]; K ordered as k = tap*32 + ch.
// A: w1r[o][k], o=lane&15, k=quad*8+j  -> ds_read_b128
// B: tile[(yrow+jy)][n+jx][quad*8..+7] -> ds_read_b128 (contiguous 1 KiB/wave)
// C/D: col(pixel)=lane&15, row(out-ch)=quad*4+reg  [verified m89/m91]
__global__ __launch_bounds__(256, 4) void head_deform2_kernel(
        const ushort_t* __restrict__ qpad, const float* __restrict__ z1,
        const float* __restrict__ z2,
        const float* __restrict__ w1a, const float* __restrict__ w2a, const float* __restrict__ b2a,
        const float* __restrict__ w1b, const float* __restrict__ w2b, const float* __restrict__ b2b,
        float* __restrict__ y1, float* __restrict__ y2) {
    __shared__ __align__(16) ushort_t tile[HALO * HALO * C];   // 20736 B
    __shared__ __align__(16) ushort_t w1r[CH * 288];           // 9216 B
    __shared__ __align__(16) ushort_t hidL[256 * CH];          // 8192 B (bf16)
    __shared__ float w2s[CO * CH];
    __shared__ float b2s[CO];
    int tid = threadIdx.x, b = blockIdx.y;
    int ox = (blockIdx.x & 15) * TILE, oy = (blockIdx.x >> 4) * TILE;
    int lane = tid & 63, wv = tid >> 6;
    int n15 = lane & 15, quad = lane >> 4;

    // stage q tile (vectorized: rows are contiguous in padded channel-last q)
    {
        const ushort_t* base = qpad + ((size_t)b * WP + oy) * WP * 32;
        uint4* tl = (uint4*)tile;
        for (int i = tid; i < 1296; i += 256) {           // 1296 = 18 rows * 72 chunks
            int yy = i / 72, r = i - yy * 72;
            tl[i] = *(const uint4*)(base + ((size_t)yy * WP + ox) * 32 + r * 8);
        }
    }
    // stage head-1 weights (reordered: w1r[o*288 + (jy*3+jx)*32 + i])
    for (int i = tid; i < CH * 288; i += 256) {
        int o = i / 288, k = i - o * 288;
        int j = k >> 5, ci = k & 31;
        w1r[i] = f2b(w1a[(o * C + ci) * 9 + j]);
    }
    for (int i = tid; i < CO * CH; i += 256) w2s[i] = w2a[i];
    if (tid < CO) b2s[tid] = b2a[tid];
    __syncthreads();

    // ---- head 1: MFMA conv ----
    {
        bf16x8 afrag[9];
#pragma unroll
        for (int j = 0; j < 9; ++j)
            afrag[j] = *(const bf16x8*)(w1r + n15 * 288 + j * 32 + quad * 8);
#pragma unroll
        for (int g = 0; g < 4; ++g) {
            int yrow = wv * 4 + g;
            f32x4 acc = {0.0f, 0.0f, 0.0f, 0.0f};
#pragma unroll
            for (int jy = 0; jy < 3; ++jy)
#pragma unroll
                for (int jx = 0; jx < 3; ++jx) {
                    const bf16x8* bp = (const bf16x8*)(tile +
                        (((yrow + jy) * HALO) + n15 + jx) * 32 + quad * 8);
                    acc = __builtin_amdgcn_mfma_f32_16x16x32_bf16(
                        afrag[jy * 3 + jx], *bp, acc, 0, 0, 0);
                }
            uint2 hv;
            hv.x = (unsigned)f2b(acc[0]) | ((unsigned)f2b(acc[1]) << 16);
            hv.y = (unsigned)f2b(acc[2]) | ((unsigned)f2b(acc[3]) << 16);
            *(uint2*)(hidL + (yrow * 16 + n15) * CH + quad * 4) = hv;
        }
    }
    // deform tail head 1 (hid is wave-local in LDS)
    {
        float hid[CH];
        const uint2* hp = (const uint2*)(hidL + tid * CH);
#pragma unroll
        for (int j = 0; j < 4; ++j) {
            uint2 hv = hp[j];
            hid[4 * j + 0] = silu_f(__uint_as_float(hv.x << 16));
            hid[4 * j + 1] = silu_f(__uint_as_float(hv.x & 0xffff0000u));
            hid[4 * j + 2] = silu_f(__uint_as_float(hv.y << 16));
            hid[4 * j + 3] = silu_f(__uint_as_float(hv.y & 0xffff0000u));
        }
        head_tail<H1, W1>(hid, w2s, b2s, z1, y1, b, ox + (tid & 15), oy + (tid >> 4));
    }
    __syncthreads();
    // stage head-2 weights
    for (int i = tid; i < CH * 288; i += 256) {
        int o = i / 288, k = i - o * 288;
        int j = k >> 5, ci = k & 31;
        w1r[i] = f2b(w1b[(o * C + ci) * 9 + j]);
    }
    for (int i = tid; i < CO * CH; i += 256) w2s[i] = w2b[i];
    if (tid < CO) b2s[tid] = b2b[tid];
    __syncthreads();

    // ---- head 2: MFMA conv ----
    {
        bf16x8 afrag[9];
#pragma unroll
        for (int j = 0; j < 9; ++j)
            afrag[j] = *(const bf16x8*)(w1r + n15 * 288 + j * 32 + quad * 8);
#pragma unroll
        for (int g = 0; g < 4; ++g) {
            int yrow = wv * 4 + g;
            f32x4 acc = {0.0f, 0.0f, 0.0f, 0.0f};
#pragma unroll
            for (int jy = 0; jy < 3; ++jy)
#pragma unroll
                for (int jx = 0; jx < 3; ++jx) {
                    const bf16x8* bp = (const bf16x8*)(tile +
                        (((yrow + jy) * HALO) + n15 + jx) * 32 + quad * 8);
                    acc = __builtin_amdgcn_mfma_f32_16x16x32_bf16(
                        afrag[jy * 3 + jx], *bp, acc, 0, 0, 0);
                }
            uint2 hv;
            hv.x = (unsigned)f2b(acc[0]) | ((unsigned)f2b(acc[1]) << 16);
            hv.y = (unsigned)f2b(acc[2]) | ((unsigned)f2b(acc[3]) << 16);
            *(uint2*)(hidL + (yrow * 16 + n15) * CH + quad * 4) = hv;
        }
    }
    // deform tail head 2
    {
        float hid[CH];
        const uint2* hp = (const uint2*)(hidL + tid * CH);
#pragma unroll
        for (int j = 0; j < 4; ++j) {
            uint2 hv = hp[j];
            hid[4 * j + 0] = silu_f(__uint_as_float(hv.x << 16));
            hid[4 * j + 1] = silu_f(__uint_as_float(hv.x & 0xffff0000u));
            hid[4 * j + 2] = silu_f(__uint_as_float(hv.y << 16));
            hid[4 * j + 3] = silu_f(__uint_as_float(hv.y & 0xffff0000u));
        }
        head_tail<H2, W2>(hid, w2s, b2s, z2, y2, b, ox + (tid & 15), oy + (tid >> 4));
    }
}

// ---- merged per-plane means (384 blocks) ----------------------------------
__global__ void mean3_kernel(const float* __restrict__ z0, const float* __restrict__ y1,
                             const float* __restrict__ y2, float* __restrict__ dall) {
    int id = blockIdx.x;
    int srcI = id >> 7, plane = id & 127;
    const float* base = (srcI == 0) ? z0 : (srcI == 1 ? y1 : y2);
    const float* src = base + (size_t)plane * HW;
    float s = 0.0f;
    for (int i = threadIdx.x; i < HW; i += blockDim.x) s += src[i];
#pragma unroll
    for (int o = 32; o > 0; o >>= 1) s += __shfl_down(s, o, 64);
    __shared__ float ls[4];
    if ((threadIdx.x & 63) == 0) ls[threadIdx.x >> 6] = s;
    __syncthreads();
    if (threadIdx.x == 0) {
        float t = ls[0] + ls[1] + ls[2] + ls[3];
        int b = plane >> 5, c = plane & 31;
        dall[b * 96 + srcI * 32 + c] = t * (1.0f / HW);
    }
}

// ---- gating MLP + softmax -> alpha[B*3] -----------------------------------
__global__ void gate_kernel(const float* __restrict__ dall,
                            const float* __restrict__ w1, const float* __restrict__ b1,
                            const float* __restrict__ w2, const float* __restrict__ b2,
                            float* __restrict__ alpha) {
    __shared__ float hid[B][32];
    int tid = threadIdx.x;
    int b = tid >> 5, j = tid & 31;
    float a = b1[j];
    for (int k = 0; k < 96; ++k) a += dall[b * 96 + k] * w1[k * 32 + j];
    hid[b][j] = silu_f(a);
    __syncthreads();
    if (j == 0) {
        float lg[3];
#pragma unroll
        for (int t = 0; t < 3; ++t) {
            float acc = b2[t];
            for (int jj = 0; jj < 32; ++jj) acc += hid[b][jj] * w2[jj * 3 + t];
            lg[t] = acc;
        }
        float mx = fmaxf(lg[0], fmaxf(lg[1], lg[2]));
        float e0 = __expf(lg[0] - mx), e1 = __expf(lg[1] - mx), e2 = __expf(lg[2] - mx);
        float inv = fast_rcp(e0 + e1 + e2);
        alpha[b * 3 + 0] = e0 * inv;
        alpha[b * 3 + 1] = e1 * inv;
        alpha[b * 3 + 2] = e2 * inv;
    }
}

// ---- fused mix + final 1x1 conv + residual --------------------------------
__global__ __launch_bounds__(256, 4) void final_kernel(
        const float* __restrict__ x,
        const float* __restrict__ z0, const float* __restrict__ y1,
        const float* __restrict__ y2, const float* __restrict__ alpha,
        const float* __restrict__ fw, float* __restrict__ out) {
    __shared__ float ws[C * C];
    for (int i = threadIdx.x; i < C * C; i += blockDim.x) ws[i] = fw[i];
    __syncthreads();
    int idx = blockIdx.x * blockDim.x + threadIdx.x;
    if (idx >= B * HW) return;
    int b = idx / HW, p = idx % HW;
    float a0 = alpha[b * 3], a1 = alpha[b * 3 + 1], a2 = alpha[b * 3 + 2];
    size_t base = (size_t)b * C * HW + p;
    float mix[C];
#pragma unroll
    for (int i = 0; i < C; ++i) {
        size_t e = base + (size_t)i * HW;
        mix[i] = a0 * z0[e] + a1 * y1[e] + a2 * y2[e];
    }
#pragma unroll 4
    for (int o = 0; o < C; ++o) {
        float acc = 0.0f;
#pragma unroll
        for (int i = 0; i < C; ++i) acc += ws[o * C + i] * mix[i];
        size_t e = base + (size_t)o * HW;
        out[e] = acc + x[e];
    }
}

// ---------------------------------------------------------------------------
extern "C" void kernel_launch(void* const* d_in, const int* in_sizes, int n_in,
                              void* d_out, int out_size, void* d_ws, size_t ws_size,
                              hipStream_t stream) {
    const float* x       = (const float*)d_in[0];
    const float* ds_dw[3] = {(const float*)d_in[1],  (const float*)d_in[7],  (const float*)d_in[13]};
    const float* ds_pw[3] = {(const float*)d_in[2],  (const float*)d_in[8],  (const float*)d_in[14]};
    const float* ds_g[3]  = {(const float*)d_in[3],  (const float*)d_in[9],  (const float*)d_in[15]};
    const float* ds_b[3]  = {(const float*)d_in[4],  (const float*)d_in[10], (const float*)d_in[16]};
    const float* ds_m[3]  = {(const float*)d_in[5],  (const float*)d_in[11], (const float*)d_in[17]};
    const float* ds_v[3]  = {(const float*)d_in[6],  (const float*)d_in[12], (const float*)d_in[18]};
    const float* qproj_w = (const float*)d_in[19];
    const float* h1_w1   = (const float*)d_in[20];
    const float* h1_w2   = (const float*)d_in[21];
    const float* h1_b2   = (const float*)d_in[22];
    const float* h2_w1   = (const float*)d_in[23];
    const float* h2_w2   = (const float*)d_in[24];
    const float* h2_b2   = (const float*)d_in[25];
    const float* r_w1    = (const float*)d_in[26];
    const float* r_b1    = (const float*)d_in[27];
    const float* r_w2    = (const float*)d_in[28];
    const float* r_b2    = (const float*)d_in[29];
    const float* final_w = (const float*)d_in[30];
    float* out = (float*)d_out;

    constexpr size_t N0 = (size_t)B * C * HW;
    constexpr size_t N1 = (size_t)B * C * HW1;
    constexpr size_t N2 = (size_t)B * C * HW2;
    constexpr size_t NQ = ((size_t)B * WP * WP * 32 + 1) / 2;   // qpad in floats

    float* w = (float*)d_ws;
    float* z0   = w; w += N0;
    float* y1   = w; w += N0;
    float* y2   = w; w += N0;
    float* z1cl = w; w += N1;
    float* z2cl = w; w += N2;
    float* s1   = w; w += N1;
    float* s2   = w; w += N2;
    ushort_t* qpad = (ushort_t*)w; w += NQ;
    float* dall  = w; w += 512;
    float* alpha = w; w += 16;
    (void)ws_size; (void)in_sizes; (void)n_in; (void)out_size;

    const int T = 256;
    auto g = [](size_t n, int t) { return (int)((n + t - 1) / t); };

    // pools + q border zero
    pool_kernel<2><<<g(N1, T), T, 0, stream>>>(x, s1, H1, W1);
    pool_kernel<4><<<g(N2, T), T, 0, stream>>>(x, s2, H2, W2);
    qpad_border_kernel<<<g(4 * 1028, T), T, 0, stream>>>(qpad);

    // ds blocks (tiled); ds0 also emits q (bf16, channel-last, padded)
    fused_ds_kernel<false, true><<<dim3((H / TILE) * (W / TILE), B), T, 0, stream>>>(
        x, ds_dw[0], ds_pw[0], ds_g[0], ds_b[0], ds_m[0], ds_v[0], qproj_w,
        z0, qpad, H, W, W / TILE);
    fused_ds_kernel<true, false><<<dim3((H1 / TILE) * (W1 / TILE), B), T, 0, stream>>>(
        s1, ds_dw[1], ds_pw[1], ds_g[1], ds_b[1], ds_m[1], ds_v[1], nullptr,
        z1cl, nullptr, H1, W1, W1 / TILE);
    fused_ds_kernel<true, false><<<dim3((H2 / TILE) * (W2 / TILE), B), T, 0, stream>>>(
        s2, ds_dw[2], ds_pw[2], ds_g[2], ds_b[2], ds_m[2], ds_v[2], nullptr,
        z2cl, nullptr, H2, W2, W2 / TILE);

    // both heads + deformable sampling (MFMA conv)
    head_deform2_kernel<<<dim3((H / TILE) * (W / TILE), B), T, 0, stream>>>(
        qpad, z1cl, z2cl, h1_w1, h1_w2, h1_b2, h2_w1, h2_w2, h2_b2, y1, y2);

    // descriptors + gate
    mean3_kernel<<<384, T, 0, stream>>>(z0, y1, y2, dall);
    gate_kernel<<<1, 128, 0, stream>>>(dall, r_w1, r_b1, r_w2, r_b2, alpha);

    // fused mix + final conv + residual
    final_kernel<<<g((size_t)B * HW, T), T, 0, stream>>>(x, z0, y1, y2, alpha, final_w, out);
}

// Round 5
// 419.136 us; speedup vs baseline: 3.9373x; 1.1982x over previous
//
#include <hip/hip_runtime.h>
#include <math.h>

// ---------------------------------------------------------------------------
// CSDM pipeline on MI355X. fp32 in/out, fp32/bf16 intermediates in d_ws.
// B=4, C=32, H=W=256. MFMA head conv, packed-f32 pointwise math,
// MLP-restructured deformable gather.
// ---------------------------------------------------------------------------

constexpr int B = 4, C = 32, H = 256, W = 256;
constexpr int HW = H * W;
constexpr int H1 = 128, W1 = 128, HW1 = H1 * W1;
constexpr int H2 = 64,  W2 = 64,  HW2 = H2 * W2;
constexpr int CH = 16;   // head hidden channels
constexpr int CO = 12;   // head output channels
constexpr int TILE = 16;
constexpr int HALO = 18;
constexpr int TAREA = HALO * HALO;   // 324
constexpr int WP = 258;              // padded q edge

typedef unsigned short ushort_t;
typedef __attribute__((ext_vector_type(8))) short bf16x8;
typedef __attribute__((ext_vector_type(4))) float f32x4;
typedef __attribute__((ext_vector_type(2))) float v2f;

static __device__ __forceinline__ float fast_rcp(float x) { return __builtin_amdgcn_rcpf(x); }
static __device__ __forceinline__ float silu_f(float x) { return x * fast_rcp(1.0f + __expf(-x)); }
static __device__ __forceinline__ v2f silu2(v2f x) {
    v2f r; r.x = silu_f(x.x); r.y = silu_f(x.y); return r;
}
static __device__ __forceinline__ float tanh_f(float x) {
    float xc = fminf(fmaxf(x, -15.0f), 15.0f);
    float e = __expf(2.0f * xc);
    return (e - 1.0f) * fast_rcp(e + 1.0f);
}
static __device__ __forceinline__ ushort_t f2b(float f) {   // fp32 -> bf16 RNE
    unsigned u = __float_as_uint(f);
    return (ushort_t)((u + 0x7fffu + ((u >> 16) & 1u)) >> 16);
}

// ---- pool by 2 (x -> s1) + qpad border zeroing folded in ------------------
__global__ void pool2_border_kernel(const float* __restrict__ x, float* __restrict__ s1,
                                    ushort_t* __restrict__ qpad) {
    int idx = blockIdx.x * blockDim.x + threadIdx.x;
    constexpr int NP = B * C * HW1;
    if (idx < NP) {
        int wo = idx % W1; int t = idx / W1;
        int ho = t % H1;   t /= H1;
        const float* src = x + ((size_t)t * H + (size_t)ho * 2) * W + (size_t)wo * 2;
        s1[idx] = (src[0] + src[1] + src[W] + src[W + 1]) * 0.25f;
        return;
    }
    int i = idx - NP;
    if (i >= 4 * 1028) return;
    int b = i / 1028, r = i % 1028;
    int y, xx;
    if (r < 258)      { y = 0;           xx = r; }
    else if (r < 516) { y = 257;         xx = r - 258; }
    else if (r < 772) { y = r - 516 + 1; xx = 0; }
    else              { y = r - 772 + 1; xx = 257; }
    uint4 z4 = {0, 0, 0, 0};
    uint4* p = (uint4*)(qpad + (((size_t)b * WP + y) * WP + xx) * 32);
    p[0] = z4; p[1] = z4; p[2] = z4; p[3] = z4;
}

// ---- pool by 2 (s1 -> s2) -------------------------------------------------
__global__ void pool4_kernel(const float* __restrict__ s1, float* __restrict__ s2) {
    int idx = blockIdx.x * blockDim.x + threadIdx.x;
    if (idx >= B * C * HW2) return;
    int wo = idx % W2; int t = idx / W2;
    int ho = t % H2;   t /= H2;
    const float* src = s1 + ((size_t)t * H1 + (size_t)ho * 2) * W1 + (size_t)wo * 2;
    s2[idx] = (src[0] + src[1] + src[W1] + src[W1 + 1]) * 0.25f;
}

// ---- fused ds_block: dwconv3 + 1x1 + BN + SiLU (+ q-proj), packed f32 -----
// CHLAST: write z channel-last [b][p][c]; else plane [b][c][p].
template<bool CHLAST, bool WITHQ>
__global__ __launch_bounds__(256, 4) void fused_ds_kernel(
        const float* __restrict__ in, const float* __restrict__ dw,
        const float* __restrict__ pw, const float* __restrict__ g,
        const float* __restrict__ bb, const float* __restrict__ m,
        const float* __restrict__ v, const float* __restrict__ qw,
        float* __restrict__ out, ushort_t* __restrict__ qout,
        int Hs, int Ws, int tilesX) {
    __shared__ unsigned tileu[16 * TAREA];     // 2-ch interleaved bf16, 20736 B
    __shared__ v2f dwp[16 * 9];                // dw pairs
    __shared__ v2f pwp[C * 16];                // pwp[ci*16+o2] = {w[2o2][ci], w[2o2+1][ci]}
    __shared__ v2f qwp[WITHQ ? C * 16 : 1];
    __shared__ v2f scale2[16], shift2[16];
    int tid = threadIdx.x;
    int b = blockIdx.y;
    int HWs = Hs * Ws;
    int ox = (blockIdx.x % tilesX) * TILE;
    int oy = (blockIdx.x / tilesX) * TILE;

    for (int i = tid; i < 16 * 9; i += 256) {
        int c2 = i / 9, j = i - c2 * 9;
        dwp[i] = (v2f){dw[(2 * c2) * 9 + j], dw[(2 * c2 + 1) * 9 + j]};
    }
    for (int i = tid; i < C * 16; i += 256) {
        int ci = i >> 4, o2 = i & 15;
        pwp[i] = (v2f){pw[(2 * o2) * C + ci], pw[(2 * o2 + 1) * C + ci]};
        if (WITHQ) qwp[i] = (v2f){qw[(2 * o2) * C + ci], qw[(2 * o2 + 1) * C + ci]};
    }
    if (tid < 16) {
        float s0 = g[2 * tid] * rsqrtf(v[2 * tid] + 1e-5f);
        float s1v = g[2 * tid + 1] * rsqrtf(v[2 * tid + 1] + 1e-5f);
        scale2[tid] = (v2f){s0, s1v};
        shift2[tid] = (v2f){bb[2 * tid] - m[2 * tid] * s0, bb[2 * tid + 1] - m[2 * tid + 1] * s1v};
    }
    const float* src = in + (size_t)b * C * HWs;
    for (int i = tid; i < 16 * TAREA; i += 256) {
        int c2 = i / TAREA, r = i - c2 * TAREA;
        int yy = r / HALO, xx = r - yy * HALO;
        int gy = oy - 1 + yy, gx = ox - 1 + xx;
        float v0 = 0.0f, v1 = 0.0f;
        if (gy >= 0 && gy < Hs && gx >= 0 && gx < Ws) {
            const float* sp = src + (size_t)(2 * c2) * HWs + gy * Ws + gx;
            v0 = sp[0]; v1 = sp[HWs];
        }
        tileu[i] = (unsigned)f2b(v0) | ((unsigned)f2b(v1) << 16);
    }
    __syncthreads();

    int tx = tid & 15, ty = tid >> 4;
    int off[9];
#pragma unroll
    for (int jy = 0; jy < 3; ++jy)
#pragma unroll
        for (int jx = 0; jx < 3; ++jx)
            off[jy * 3 + jx] = (ty + jy) * HALO + tx + jx;

    v2f t2[16];
#pragma unroll
    for (int c2 = 0; c2 < 16; ++c2) {
        v2f s = {0.0f, 0.0f};
        const unsigned* tp = tileu + c2 * TAREA;
#pragma unroll
        for (int j = 0; j < 9; ++j) {
            unsigned u = tp[off[j]];
            v2f val = {__uint_as_float(u << 16), __uint_as_float(u & 0xffff0000u)};
            s += dwp[c2 * 9 + j] * val;
        }
        t2[c2] = s;
    }

    // 1x1: acc2[o2] = {out 2o2, out 2o2+1}
    v2f acc2[16];
#pragma unroll
    for (int o2 = 0; o2 < 16; ++o2) acc2[o2] = (v2f){0.0f, 0.0f};
#pragma unroll
    for (int i2 = 0; i2 < 16; ++i2) {
        float ta = t2[i2].x, tb = t2[i2].y;
        const v2f* r0 = pwp + (2 * i2) * 16;
        const v2f* r1 = r0 + 16;
#pragma unroll
        for (int o2 = 0; o2 < 16; ++o2)
            acc2[o2] += r0[o2] * ta + r1[o2] * tb;
    }
#pragma unroll
    for (int o2 = 0; o2 < 16; ++o2)
        acc2[o2] = silu2(acc2[o2] * scale2[o2] + shift2[o2]);

    int px = ox + tx, py = oy + ty;
    int p = py * Ws + px;
    if (CHLAST) {
        float4* dst = (float4*)(out + ((size_t)b * HWs + p) * C);
#pragma unroll
        for (int j = 0; j < 8; ++j)
            dst[j] = make_float4(acc2[2 * j].x, acc2[2 * j].y, acc2[2 * j + 1].x, acc2[2 * j + 1].y);
    } else {
        float* dst = out + (size_t)b * C * HWs + p;
#pragma unroll
        for (int o2 = 0; o2 < 16; ++o2) {
            dst[(size_t)(2 * o2) * HWs] = acc2[o2].x;
            dst[(size_t)(2 * o2 + 1) * HWs] = acc2[o2].y;
        }
    }
    if (WITHQ) {
        v2f q2[16];
#pragma unroll
        for (int o2 = 0; o2 < 16; ++o2) q2[o2] = (v2f){0.0f, 0.0f};
#pragma unroll
        for (int i2 = 0; i2 < 16; ++i2) {
            float ta = acc2[i2].x, tb = acc2[i2].y;
            const v2f* r0 = qwp + (2 * i2) * 16;
            const v2f* r1 = r0 + 16;
#pragma unroll
            for (int o2 = 0; o2 < 16; ++o2)
                q2[o2] += r0[o2] * ta + r1[o2] * tb;
        }
        unsigned up[16];
#pragma unroll
        for (int j = 0; j < 16; ++j)
            up[j] = (unsigned)f2b(q2[j].x) | ((unsigned)f2b(q2[j].y) << 16);
        uint4* qd = (uint4*)(qout + (((size_t)b * WP + py + 1) * WP + px + 1) * 32);
#pragma unroll
        for (int j = 0; j < 4; ++j)
            qd[j] = make_uint4(up[4 * j], up[4 * j + 1], up[4 * j + 2], up[4 * j + 3]);
    }
}

// ---- deform tail ----------------------------------------------------------
template<int HC, int WC>
static __device__ __forceinline__ void head_tail(
        const float* hid, const float* w2s, const float* b2s,
        const float* __restrict__ zb, float* __restrict__ ydst,
        int px, int py) {
    float o12[CO];
#pragma unroll
    for (int j = 0; j < CO; ++j) {
        float a = b2s[j];
#pragma unroll
        for (int i = 0; i < CH; ++i) a += w2s[j * CH + i] * hid[i];
        o12[j] = a;
    }
    float mx = fmaxf(fmaxf(o12[8], o12[9]), fmaxf(o12[10], o12[11]));
    float e0 = __expf(o12[8] - mx), e1 = __expf(o12[9] - mx);
    float e2 = __expf(o12[10] - mx), e3 = __expf(o12[11] - mx);
    float inv = fast_rcp(e0 + e1 + e2 + e3);
    float wk4[4] = {e0 * inv, e1 * inv, e2 * inv, e3 * inv};

    float xc = (px + 0.5f) * ((float)WC / (float)W) - 0.5f;
    float yc = (py + 0.5f) * ((float)HC / (float)H) - 0.5f;

    int zoff[16]; float wgt[16];
#pragma unroll
    for (int k = 0; k < 4; ++k) {
        float ix = fminf(fmaxf(xc + 2.0f * tanh_f(o12[2 * k]),     0.0f), (float)(WC - 1));
        float iy = fminf(fmaxf(yc + 2.0f * tanh_f(o12[2 * k + 1]), 0.0f), (float)(HC - 1));
        float x0f = floorf(ix), y0f = floorf(iy);
        int x0 = (int)x0f, y0 = (int)y0f;
        int x1 = min(x0 + 1, WC - 1), y1 = min(y0 + 1, HC - 1);
        float wx = ix - x0f, wy = iy - y0f;
        float wk = wk4[k];
        zoff[4 * k + 0] = (y0 * WC + x0) * C; wgt[4 * k + 0] = (1.0f - wx) * (1.0f - wy) * wk;
        zoff[4 * k + 1] = (y0 * WC + x1) * C; wgt[4 * k + 1] = wx * (1.0f - wy) * wk;
        zoff[4 * k + 2] = (y1 * WC + x0) * C; wgt[4 * k + 2] = (1.0f - wx) * wy * wk;
        zoff[4 * k + 3] = (y1 * WC + x1) * C; wgt[4 * k + 3] = wx * wy * wk;
    }
#pragma unroll 1
    for (int c4 = 0; c4 < 8; ++c4) {
        f32x4 a = {0.0f, 0.0f, 0.0f, 0.0f};
#pragma unroll
        for (int j = 0; j < 16; ++j) {
            const f32x4 vv = *(const f32x4*)(zb + zoff[j] + c4 * 4);
            a += wgt[j] * vv;
        }
        float* dst = ydst + (size_t)(c4 * 4) * HW;
        dst[0] = a[0]; dst[HW] = a[1]; dst[2 * HW] = a[2]; dst[3 * HW] = a[3];
    }
}

// ---- both heads: MFMA 3x3 conv (swizzled tile) + deform tail --------------
__global__ __launch_bounds__(256, 4) void head_deform2_kernel(
        const ushort_t* __restrict__ qpad, const float* __restrict__ z1,
        const float* __restrict__ z2,
        const float* __restrict__ w1a, const float* __restrict__ w2a, const float* __restrict__ b2a,
        const float* __restrict__ w1b, const float* __restrict__ w2b, const float* __restrict__ b2b,
        float* __restrict__ y1, float* __restrict__ y2) {
    __shared__ __align__(16) ushort_t tile[HALO * HALO * C];     // 20736 B
    __shared__ __align__(16) unsigned char ovl[CH * 288 * 2];    // w1r (9216) / hidL (8192) overlay
    __shared__ float w2s[CO * CH];
    __shared__ float b2s[CO];
    ushort_t* w1r = (ushort_t*)ovl;
    ushort_t* hidL = (ushort_t*)ovl;
    int tid = threadIdx.x, b = blockIdx.y;
    int ox = (blockIdx.x & 15) * TILE, oy = (blockIdx.x >> 4) * TILE;
    int lane = tid & 63, wv = tid >> 6;
    int n15 = lane & 15, quad = lane >> 4;
    int tx = tid & 15, ty = tid >> 4;

    // stage q tile with chunk swizzle: slot = quad ^ (col&3) ^ ((col>>2)&3)
    {
        const ushort_t* base = qpad + ((size_t)b * WP + oy) * WP * 32;
        uint4* tl = (uint4*)tile;
        for (int i = tid; i < 1296; i += 256) {
            int yy = i / 72, r = i - yy * 72;
            int col = r >> 2, ch = r & 3;
            int slot = (ch ^ (col & 3) ^ ((col >> 2) & 3)) & 3;
            tl[(yy * HALO + col) * 4 + slot] =
                *(const uint4*)(base + ((size_t)yy * WP + ox + col) * 32 + ch * 8);
        }
    }
    for (int i = tid; i < CH * 288; i += 256) {
        int o = i / 288, k = i - o * 288;
        int j = k >> 5, ci = k & 31;
        w1r[i] = f2b(w1a[(o * C + ci) * 9 + j]);
    }
    for (int i = tid; i < CO * CH; i += 256) w2s[i] = w2a[i];
    if (tid < CO) b2s[tid] = b2a[tid];
    __syncthreads();

    // ---- head 1 ----
    {
        bf16x8 afrag[9];
#pragma unroll
        for (int j = 0; j < 9; ++j)
            afrag[j] = *(const bf16x8*)(w1r + n15 * 288 + j * 32 + quad * 8);
        __syncthreads();   // w1r free -> hidL may be written
#pragma unroll
        for (int g = 0; g < 4; ++g) {
            int yrow = wv * 4 + g;
            f32x4 acc = {0.0f, 0.0f, 0.0f, 0.0f};
#pragma unroll
            for (int jy = 0; jy < 3; ++jy)
#pragma unroll
                for (int jx = 0; jx < 3; ++jx) {
                    int col = n15 + jx;
                    int slot = (quad ^ (col & 3) ^ ((col >> 2) & 3)) & 3;
                    const bf16x8* bp = (const bf16x8*)(tile +
                        ((yrow + jy) * HALO + col) * 32 + slot * 8);
                    acc = __builtin_amdgcn_mfma_f32_16x16x32_bf16(
                        afrag[jy * 3 + jx], *bp, acc, 0, 0, 0);
                }
            uint2 hv;
            hv.x = (unsigned)f2b(acc[0]) | ((unsigned)f2b(acc[1]) << 16);
            hv.y = (unsigned)f2b(acc[2]) | ((unsigned)f2b(acc[3]) << 16);
            *(uint2*)(hidL + (yrow * 16 + n15) * CH + quad * 4) = hv;
        }
    }
    {
        float hid[CH];
        const uint2* hp = (const uint2*)(hidL + tid * CH);
#pragma unroll
        for (int j = 0; j < 4; ++j) {
            uint2 hv = hp[j];
            hid[4 * j + 0] = silu_f(__uint_as_float(hv.x << 16));
            hid[4 * j + 1] = silu_f(__uint_as_float(hv.x & 0xffff0000u));
            hid[4 * j + 2] = silu_f(__uint_as_float(hv.y << 16));
            hid[4 * j + 3] = silu_f(__uint_as_float(hv.y & 0xffff0000u));
        }
        head_tail<H1, W1>(hid, w2s, b2s, z1 + (size_t)b * HW1 * C,
                          y1 + (size_t)b * C * HW + (oy + ty) * W + ox + tx,
                          ox + tx, oy + ty);
    }
    __syncthreads();
    for (int i = tid; i < CH * 288; i += 256) {
        int o = i / 288, k = i - o * 288;
        int j = k >> 5, ci = k & 31;
        w1r[i] = f2b(w1b[(o * C + ci) * 9 + j]);
    }
    for (int i = tid; i < CO * CH; i += 256) w2s[i] = w2b[i];
    if (tid < CO) b2s[tid] = b2b[tid];
    __syncthreads();

    // ---- head 2 ----
    {
        bf16x8 afrag[9];
#pragma unroll
        for (int j = 0; j < 9; ++j)
            afrag[j] = *(const bf16x8*)(w1r + n15 * 288 + j * 32 + quad * 8);
        __syncthreads();
#pragma unroll
        for (int g = 0; g < 4; ++g) {
            int yrow = wv * 4 + g;
            f32x4 acc = {0.0f, 0.0f, 0.0f, 0.0f};
#pragma unroll
            for (int jy = 0; jy < 3; ++jy)
#pragma unroll
                for (int jx = 0; jx < 3; ++jx) {
                    int col = n15 + jx;
                    int slot = (quad ^ (col & 3) ^ ((col >> 2) & 3)) & 3;
                    const bf16x8* bp = (const bf16x8*)(tile +
                        ((yrow + jy) * HALO + col) * 32 + slot * 8);
                    acc = __builtin_amdgcn_mfma_f32_16x16x32_bf16(
                        afrag[jy * 3 + jx], *bp, acc, 0, 0, 0);
                }
            uint2 hv;
            hv.x = (unsigned)f2b(acc[0]) | ((unsigned)f2b(acc[1]) << 16);
            hv.y = (unsigned)f2b(acc[2]) | ((unsigned)f2b(acc[3]) << 16);
            *(uint2*)(hidL + (yrow * 16 + n15) * CH + quad * 4) = hv;
        }
    }
    {
        float hid[CH];
        const uint2* hp = (const uint2*)(hidL + tid * CH);
#pragma unroll
        for (int j = 0; j < 4; ++j) {
            uint2 hv = hp[j];
            hid[4 * j + 0] = silu_f(__uint_as_float(hv.x << 16));
            hid[4 * j + 1] = silu_f(__uint_as_float(hv.x & 0xffff0000u));
            hid[4 * j + 2] = silu_f(__uint_as_float(hv.y << 16));
            hid[4 * j + 3] = silu_f(__uint_as_float(hv.y & 0xffff0000u));
        }
        head_tail<H2, W2>(hid, w2s, b2s, z2 + (size_t)b * HW2 * C,
                          y2 + (size_t)b * C * HW + (oy + ty) * W + ox + tx,
                          ox + tx, oy + ty);
    }
}

// ---- merged per-plane means (384 blocks, float4) --------------------------
__global__ void mean3_kernel(const float* __restrict__ z0, const float* __restrict__ y1,
                             const float* __restrict__ y2, float* __restrict__ dall) {
    int id = blockIdx.x;
    int srcI = id >> 7, plane = id & 127;
    const float* base = (srcI == 0) ? z0 : (srcI == 1 ? y1 : y2);
    const float4* src = (const float4*)(base + (size_t)plane * HW);
    float s = 0.0f;
    for (int i = threadIdx.x; i < HW / 4; i += blockDim.x) {
        float4 f = src[i];
        s += f.x + f.y + f.z + f.w;
    }
#pragma unroll
    for (int o = 32; o > 0; o >>= 1) s += __shfl_down(s, o, 64);
    __shared__ float ls[4];
    if ((threadIdx.x & 63) == 0) ls[threadIdx.x >> 6] = s;
    __syncthreads();
    if (threadIdx.x == 0) {
        float t = ls[0] + ls[1] + ls[2] + ls[3];
        int b = plane >> 5, c = plane & 31;
        dall[b * 96 + srcI * 32 + c] = t * (1.0f / HW);
    }
}

// ---- gating MLP + softmax -> alpha[B*3] -----------------------------------
__global__ void gate_kernel(const float* __restrict__ dall,
                            const float* __restrict__ w1, const float* __restrict__ b1,
                            const float* __restrict__ w2, const float* __restrict__ b2,
                            float* __restrict__ alpha) {
    __shared__ float hid[B][32];
    int tid = threadIdx.x;
    int b = tid >> 5, j = tid & 31;
    float a = b1[j];
    for (int k = 0; k < 96; ++k) a += dall[b * 96 + k] * w1[k * 32 + j];
    hid[b][j] = silu_f(a);
    __syncthreads();
    if (j == 0) {
        float lg[3];
#pragma unroll
        for (int t = 0; t < 3; ++t) {
            float acc = b2[t];
            for (int jj = 0; jj < 32; ++jj) acc += hid[b][jj] * w2[jj * 3 + t];
            lg[t] = acc;
        }
        float mx = fmaxf(lg[0], fmaxf(lg[1], lg[2]));
        float e0 = __expf(lg[0] - mx), e1 = __expf(lg[1] - mx), e2 = __expf(lg[2] - mx);
        float inv = fast_rcp(e0 + e1 + e2);
        alpha[b * 3 + 0] = e0 * inv;
        alpha[b * 3 + 1] = e1 * inv;
        alpha[b * 3 + 2] = e2 * inv;
    }
}

// ---- fused mix + final 1x1 conv + residual (2 pixels/thread, packed) ------
__global__ __launch_bounds__(256, 4) void final_kernel(
        const float* __restrict__ x,
        const float* __restrict__ z0, const float* __restrict__ y1,
        const float* __restrict__ y2, const float* __restrict__ alpha,
        const float* __restrict__ fw, float* __restrict__ out) {
    __shared__ float ws[C * C];
    for (int i = threadIdx.x; i < C * C; i += blockDim.x) ws[i] = fw[i];
    __syncthreads();
    int idx = blockIdx.x * blockDim.x + threadIdx.x;
    constexpr int HP = HW / 2;
    if (idx >= B * HP) return;
    int b = idx / HP, p = (idx - b * HP) * 2;
    float a0 = alpha[b * 3], a1 = alpha[b * 3 + 1], a2 = alpha[b * 3 + 2];
    size_t base = (size_t)b * C * HW + p;
    v2f mix[C];
#pragma unroll
    for (int i = 0; i < C; ++i) {
        size_t e = base + (size_t)i * HW;
        v2f za = *(const v2f*)(z0 + e);
        v2f ya = *(const v2f*)(y1 + e);
        v2f yb = *(const v2f*)(y2 + e);
        mix[i] = a0 * za + a1 * ya + a2 * yb;
    }
#pragma unroll 4
    for (int o = 0; o < C; ++o) {
        v2f acc = {0.0f, 0.0f};
#pragma unroll
        for (int i = 0; i < C; ++i) acc += ws[o * C + i] * mix[i];
        size_t e = base + (size_t)o * HW;
        v2f xr = *(const v2f*)(x + e);
        *(v2f*)(out + e) = acc + xr;
    }
}

// ---------------------------------------------------------------------------
extern "C" void kernel_launch(void* const* d_in, const int* in_sizes, int n_in,
                              void* d_out, int out_size, void* d_ws, size_t ws_size,
                              hipStream_t stream) {
    const float* x       = (const float*)d_in[0];
    const float* ds_dw[3] = {(const float*)d_in[1],  (const float*)d_in[7],  (const float*)d_in[13]};
    const float* ds_pw[3] = {(const float*)d_in[2],  (const float*)d_in[8],  (const float*)d_in[14]};
    const float* ds_g[3]  = {(const float*)d_in[3],  (const float*)d_in[9],  (const float*)d_in[15]};
    const float* ds_b[3]  = {(const float*)d_in[4],  (const float*)d_in[10], (const float*)d_in[16]};
    const float* ds_m[3]  = {(const float*)d_in[5],  (const float*)d_in[11], (const float*)d_in[17]};
    const float* ds_v[3]  = {(const float*)d_in[6],  (const float*)d_in[12], (const float*)d_in[18]};
    const float* qproj_w = (const float*)d_in[19];
    const float* h1_w1   = (const float*)d_in[20];
    const float* h1_w2   = (const float*)d_in[21];
    const float* h1_b2   = (const float*)d_in[22];
    const float* h2_w1   = (const float*)d_in[23];
    const float* h2_w2   = (const float*)d_in[24];
    const float* h2_b2   = (const float*)d_in[25];
    const float* r_w1    = (const float*)d_in[26];
    const float* r_b1    = (const float*)d_in[27];
    const float* r_w2    = (const float*)d_in[28];
    const float* r_b2    = (const float*)d_in[29];
    const float* final_w = (const float*)d_in[30];
    float* out = (float*)d_out;

    constexpr size_t N0 = (size_t)B * C * HW;
    constexpr size_t N1 = (size_t)B * C * HW1;
    constexpr size_t N2 = (size_t)B * C * HW2;
    constexpr size_t NQ = ((size_t)B * WP * WP * 32 + 1) / 2;   // qpad (u16) in floats

    float* w = (float*)d_ws;
    float* z0   = w; w += N0;
    float* y1   = w; w += N0;
    float* y2   = w; w += N0;
    float* z1cl = w; w += N1;
    float* z2cl = w; w += N2;
    float* s1   = w; w += N1;
    float* s2   = w; w += N2;
    ushort_t* qpad = (ushort_t*)w; w += NQ;
    float* dall  = w; w += 512;
    float* alpha = w; w += 16;
    (void)ws_size; (void)in_sizes; (void)n_in; (void)out_size;

    const int T = 256;
    auto g = [](size_t n, int t) { return (int)((n + t - 1) / t); };

    pool2_border_kernel<<<g(N1 + 4 * 1028, T), T, 0, stream>>>(x, s1, qpad);
    pool4_kernel<<<g(N2, T), T, 0, stream>>>(s1, s2);

    fused_ds_kernel<false, true><<<dim3((H / TILE) * (W / TILE), B), T, 0, stream>>>(
        x, ds_dw[0], ds_pw[0], ds_g[0], ds_b[0], ds_m[0], ds_v[0], qproj_w,
        z0, qpad, H, W, W / TILE);
    fused_ds_kernel<true, false><<<dim3((H1 / TILE) * (W1 / TILE), B), T, 0, stream>>>(
        s1, ds_dw[1], ds_pw[1], ds_g[1], ds_b[1], ds_m[1], ds_v[1], nullptr,
        z1cl, nullptr, H1, W1, W1 / TILE);
    fused_ds_kernel<true, false><<<dim3((H2 / TILE) * (W2 / TILE), B), T, 0, stream>>>(
        s2, ds_dw[2], ds_pw[2], ds_g[2], ds_b[2], ds_m[2], ds_v[2], nullptr,
        z2cl, nullptr, H2, W2, W2 / TILE);

    head_deform2_kernel<<<dim3((H / TILE) * (W / TILE), B), T, 0, stream>>>(
        qpad, z1cl, z2cl, h1_w1, h1_w2, h1_b2, h2_w1, h2_w2, h2_b2, y1, y2);

    mean3_kernel<<<384, T, 0, stream>>>(z0, y1, y2, dall);
    gate_kernel<<<1, 128, 0, stream>>>(dall, r_w1, r_b1, r_w2, r_b2, alpha);

    final_kernel<<<g((size_t)B * HW / 2, T), T, 0, stream>>>(x, z0, y1, y2, alpha, final_w, out);
}